// Round 5
// baseline (143.141 us; speedup 1.0000x reference)
//
#include <hip/hip_runtime.h>
#include <math.h>

#define NN    8192
#define CIN   256
#define COUT  128
#define MAXEG 256      // max edges kept per row (mean ~82, sigma ~9 -> 19 sigma)
#define ROWS  8        // rows per persistent block
#define NBLK  (NN / ROWS)

typedef unsigned uvec4 __attribute__((ext_vector_type(4)));

// Non-draining barrier: waits LDS ops only (lgkmcnt), leaves global loads
// (prefetch of next adjacency row) in flight across the barrier. __syncthreads
// would emit s_waitcnt vmcnt(0) and serialize the stream.
__device__ __forceinline__ void bar_lds() {
    asm volatile("s_waitcnt lgkmcnt(0)" ::: "memory");
    __builtin_amdgcn_s_barrier();
}

// ---------------------------------------------------------------------------
// Kernel 1: h = X@W + b ; f1 = h@v0 ; f2 = h@v1  (fp32, 16 rows x 128 cols/blk)
// ---------------------------------------------------------------------------
__global__ __launch_bounds__(256) void k1_gemm(
    const float* __restrict__ X, const float* __restrict__ W,
    const float* __restrict__ b, const float* __restrict__ v0,
    const float* __restrict__ v1,
    float* __restrict__ h, float* __restrict__ f1, float* __restrict__ f2)
{
    __shared__ float Xs[16][32];
    const int tid = threadIdx.x;
    const int ct  = tid & 63;
    const int rg  = tid >> 6;
    const int c   = ct * 2;
    const int row0 = blockIdx.x * 16;

    float acc[4][2] = {{0.f,0.f},{0.f,0.f},{0.f,0.f},{0.f,0.f}};

    for (int kc = 0; kc < CIN; kc += 32) {
        if (tid < 128) {
            const int r = tid >> 3, q = tid & 7;
            const float4 xv = *(const float4*)(X + (size_t)(row0 + r) * CIN + kc + q * 4);
            *(float4*)&Xs[r][q * 4] = xv;
        }
        float2 wv[32];
        #pragma unroll
        for (int kk = 0; kk < 32; ++kk)
            wv[kk] = *(const float2*)(W + (size_t)(kc + kk) * COUT + c);
        __syncthreads();

        #pragma unroll
        for (int rr = 0; rr < 4; ++rr) {
            const int lr = rg * 4 + rr;
            #pragma unroll
            for (int k4 = 0; k4 < 8; ++k4) {
                const float4 xv = *(const float4*)&Xs[lr][k4 * 4];
                acc[rr][0] += xv.x * wv[k4*4+0].x; acc[rr][1] += xv.x * wv[k4*4+0].y;
                acc[rr][0] += xv.y * wv[k4*4+1].x; acc[rr][1] += xv.y * wv[k4*4+1].y;
                acc[rr][0] += xv.z * wv[k4*4+2].x; acc[rr][1] += xv.z * wv[k4*4+2].y;
                acc[rr][0] += xv.w * wv[k4*4+3].x; acc[rr][1] += xv.w * wv[k4*4+3].y;
            }
        }
        __syncthreads();
    }

    const float b0 = b[c], b1 = b[c+1];
    const float v00 = v0[c], v01 = v0[c+1];
    const float v10 = v1[c], v11 = v1[c+1];

    #pragma unroll
    for (int rr = 0; rr < 4; ++rr) {
        const int row = row0 + rg * 4 + rr;
        const float h0 = acc[rr][0] + b0;
        const float h1 = acc[rr][1] + b1;
        *(float2*)(h + (size_t)row * COUT + c) = make_float2(h0, h1);
        float p0 = h0 * v00 + h1 * v01;
        float p1 = h0 * v10 + h1 * v11;
        #pragma unroll
        for (int off = 32; off; off >>= 1) {
            p0 += __shfl_down(p0, off, 64);
            p1 += __shfl_down(p1, off, 64);
        }
        if (ct == 0) { f1[row] = p0; f2[row] = p1; }
    }
}

// ---------------------------------------------------------------------------
// Fused scan + softmax + gather for one row, adjacency already in registers.
// ---------------------------------------------------------------------------
__device__ __forceinline__ void process_row(
    const uvec4 (&cur)[8], const int row, const int tid,
    const float* __restrict__ h, const float* __restrict__ f1,
    const float* __restrict__ f2, float* __restrict__ out,
    unsigned& scnt, unsigned short* sjl, float* vl, float* red,
    float2 (*sacc)[64])
{
    if (tid == 0) scnt = 0;
    bar_lds();  // B1: scnt zeroed; prev row's LDS reads all completed earlier

    // ---- compact: one LDS atomic per lane-with-edges (popcount base) ----
    #pragma unroll
    for (int it = 0; it < 8; ++it) {
        const uvec4 v = cur[it];
        if (v.x | v.y | v.z | v.w) {
            const int j0 = (tid + it * 256) * 4;
            const unsigned c4 = (v.x ? 1u : 0u) + (v.y ? 1u : 0u) +
                                (v.z ? 1u : 0u) + (v.w ? 1u : 0u);
            unsigned p = atomicAdd(&scnt, c4);
            if (v.x) { if (p < MAXEG) sjl[p] = (unsigned short)(j0    ); ++p; }
            if (v.y) { if (p < MAXEG) sjl[p] = (unsigned short)(j0 + 1); ++p; }
            if (v.z) { if (p < MAXEG) sjl[p] = (unsigned short)(j0 + 2); ++p; }
            if (v.w) { if (p < MAXEG) sjl[p] = (unsigned short)(j0 + 3); ++p; }
        }
    }
    bar_lds();  // B2: edge list complete

    const int n = min((int)scnt, (int)MAXEG);
    if (n > 0) {
        // ---- sigmoid, one edge per thread (n <= 256) ----
        float m = -1e30f;
        if (tid < n) {
            const float x = f1[row] + f2[sjl[tid]];
            const float s = 1.f / (1.f + __expf(-x)) - 0.5f;
            vl[tid] = s;
            m = s;
        }
        #pragma unroll
        for (int off = 32; off; off >>= 1) m = fmaxf(m, __shfl_down(m, off, 64));
        if ((tid & 63) == 0) red[tid >> 6] = m;
        bar_lds();  // B3
        m = fmaxf(fmaxf(red[0], red[1]), fmaxf(red[2], red[3]));

        float s = 0.f;
        if (tid < n) {
            s = __expf(vl[tid] - m);
            vl[tid] = s;
        }
        #pragma unroll
        for (int off = 32; off; off >>= 1) s += __shfl_down(s, off, 64);
        if ((tid & 63) == 0) red[4 + (tid >> 6)] = s;
        bar_lds();  // B4
        const float inv = 1.f / (red[4] + red[5] + red[6] + red[7]);

        // ---- weighted sum of h rows: 4 wave-groups, float2, 4-deep ----
        const int g  = tid >> 6;
        const int ct = tid & 63;
        const int c  = ct * 2;
        float ax = 0.f, ay = 0.f;
        int p = g;
        for (; p + 12 < n; p += 16) {
            const int   j0 = sjl[p],  j1 = sjl[p + 4], j2 = sjl[p + 8], j3 = sjl[p + 12];
            const float w0 = vl[p],   w1 = vl[p + 4],  w2 = vl[p + 8],  w3 = vl[p + 12];
            const float2 a0 = *(const float2*)(h + (size_t)j0 * COUT + c);
            const float2 a1 = *(const float2*)(h + (size_t)j1 * COUT + c);
            const float2 a2 = *(const float2*)(h + (size_t)j2 * COUT + c);
            const float2 a3 = *(const float2*)(h + (size_t)j3 * COUT + c);
            ax += w0 * a0.x + w1 * a1.x + w2 * a2.x + w3 * a3.x;
            ay += w0 * a0.y + w1 * a1.y + w2 * a2.y + w3 * a3.y;
        }
        for (; p < n; p += 4) {
            const int   j = sjl[p];
            const float w = vl[p];
            const float2 a = *(const float2*)(h + (size_t)j * COUT + c);
            ax += w * a.x;
            ay += w * a.y;
        }
        sacc[g][ct] = make_float2(ax, ay);
        bar_lds();  // B5
        if (tid < 64) {
            const float2 r0 = sacc[0][tid], r1 = sacc[1][tid];
            const float2 r2 = sacc[2][tid], r3 = sacc[3][tid];
            float2 r;
            r.x = (r0.x + r1.x + r2.x + r3.x) * inv;
            r.y = (r0.y + r1.y + r2.y + r3.y) * inv;
            *(float2*)(out + (size_t)row * COUT + tid * 2) = r;
        }
    } else {
        if (tid < 64)
            *(float2*)(out + (size_t)row * COUT + tid * 2) = make_float2(0.f, 0.f);
    }
}

#define PREFETCH(BUF, PROW)                                                    \
    {                                                                          \
        const uvec4* rpn = (const uvec4*)(adj + (size_t)(PROW) * NN) + tid;    \
        _Pragma("unroll")                                                      \
        for (int it = 0; it < 8; ++it)                                         \
            BUF[it] = __builtin_nontemporal_load(rpn + it * 256);              \
    }

// ---------------------------------------------------------------------------
// Kernel 2: persistent fused scan+softmax+gather. 1024 blocks x 8 rows.
// Double-buffered adjacency prefetch kept in flight across non-draining
// barriers -> HBM stream overlaps compaction/softmax/L2-gather.
// ---------------------------------------------------------------------------
__global__ __launch_bounds__(256) void k2_fused(
    const float* __restrict__ adj, const float* __restrict__ h,
    const float* __restrict__ f1, const float* __restrict__ f2,
    float* __restrict__ out)
{
    __shared__ unsigned scnt;
    __shared__ unsigned short sjl[MAXEG];
    __shared__ float  vl[MAXEG];
    __shared__ float  red[8];
    __shared__ float2 sacc[4][64];

    const int tid  = threadIdx.x;
    const int row0 = blockIdx.x * ROWS;

    uvec4 va[8], vb[8];
    PREFETCH(va, row0)

    #pragma unroll 1
    for (int rp = 0; rp < ROWS; rp += 2) {
        PREFETCH(vb, row0 + rp + 1)
        process_row(va, row0 + rp, tid, h, f1, f2, out, scnt, sjl, vl, red, sacc);
        if (rp + 2 < ROWS) PREFETCH(va, row0 + rp + 2)
        process_row(vb, row0 + rp + 1, tid, h, f1, f2, out, scnt, sjl, vl, red, sacc);
    }
}

extern "C" void kernel_launch(void* const* d_in, const int* in_sizes, int n_in,
                              void* d_out, int out_size, void* d_ws, size_t ws_size,
                              hipStream_t stream) {
    const float* X   = (const float*)d_in[0];
    const float* adj = (const float*)d_in[1];
    const float* W   = (const float*)d_in[2];
    const float* b   = (const float*)d_in[3];
    const float* v0  = (const float*)d_in[4];
    const float* v1  = (const float*)d_in[5];
    float* out = (float*)d_out;

    float* h  = (float*)d_ws;                 // 8192*128 f32 = 4 MB
    float* f1 = h + (size_t)NN * COUT;        // 32 KB
    float* f2 = f1 + NN;                      // 32 KB

    k1_gemm<<<NN / 16, 256, 0, stream>>>(X, W, b, v0, v1, h, f1, f2);
    k2_fused<<<NBLK, 256, 0, stream>>>(adj, h, f1, f2, out);
}

// Round 6
// 99.794 us; speedup vs baseline: 1.4344x; 1.4344x over previous
//
#include <hip/hip_runtime.h>
#include <math.h>

#define NN    8192
#define CIN   256
#define COUT  128
#define MAXEG 256      // max edges kept per row (mean ~82, sigma ~9 -> 19 sigma)

typedef unsigned uvec4 __attribute__((ext_vector_type(4)));

// ---------------------------------------------------------------------------
// Kernel 1: h = X@W + b ; f1 = h@v0 ; f2 = h@v1  (fp32, 16 rows x 128 cols/blk)
// ---------------------------------------------------------------------------
__global__ __launch_bounds__(256) void k1_gemm(
    const float* __restrict__ X, const float* __restrict__ W,
    const float* __restrict__ b, const float* __restrict__ v0,
    const float* __restrict__ v1,
    float* __restrict__ h, float* __restrict__ f1, float* __restrict__ f2)
{
    __shared__ float Xs[16][32];
    const int tid = threadIdx.x;
    const int ct  = tid & 63;
    const int rg  = tid >> 6;
    const int c   = ct * 2;
    const int row0 = blockIdx.x * 16;

    float acc[4][2] = {{0.f,0.f},{0.f,0.f},{0.f,0.f},{0.f,0.f}};

    for (int kc = 0; kc < CIN; kc += 32) {
        if (tid < 128) {
            const int r = tid >> 3, q = tid & 7;
            const float4 xv = *(const float4*)(X + (size_t)(row0 + r) * CIN + kc + q * 4);
            *(float4*)&Xs[r][q * 4] = xv;
        }
        float2 wv[32];
        #pragma unroll
        for (int kk = 0; kk < 32; ++kk)
            wv[kk] = *(const float2*)(W + (size_t)(kc + kk) * COUT + c);
        __syncthreads();

        #pragma unroll
        for (int rr = 0; rr < 4; ++rr) {
            const int lr = rg * 4 + rr;
            #pragma unroll
            for (int k4 = 0; k4 < 8; ++k4) {
                const float4 xv = *(const float4*)&Xs[lr][k4 * 4];
                acc[rr][0] += xv.x * wv[k4*4+0].x; acc[rr][1] += xv.x * wv[k4*4+0].y;
                acc[rr][0] += xv.y * wv[k4*4+1].x; acc[rr][1] += xv.y * wv[k4*4+1].y;
                acc[rr][0] += xv.z * wv[k4*4+2].x; acc[rr][1] += xv.z * wv[k4*4+2].y;
                acc[rr][0] += xv.w * wv[k4*4+3].x; acc[rr][1] += xv.w * wv[k4*4+3].y;
            }
        }
        __syncthreads();
    }

    const float b0 = b[c], b1 = b[c+1];
    const float v00 = v0[c], v01 = v0[c+1];
    const float v10 = v1[c], v11 = v1[c+1];

    #pragma unroll
    for (int rr = 0; rr < 4; ++rr) {
        const int row = row0 + rg * 4 + rr;
        const float h0 = acc[rr][0] + b0;
        const float h1 = acc[rr][1] + b1;
        *(float2*)(h + (size_t)row * COUT + c) = make_float2(h0, h1);
        float p0 = h0 * v00 + h1 * v01;
        float p1 = h0 * v10 + h1 * v11;
        #pragma unroll
        for (int off = 32; off; off >>= 1) {
            p0 += __shfl_down(p0, off, 64);
            p1 += __shfl_down(p1, off, 64);
        }
        if (ct == 0) { f1[row] = p0; f2[row] = p1; }
    }
}

// ---------------------------------------------------------------------------
// Kernel 2: wave-per-row adjacency scan. No block barriers -> waves free-run,
// HBM pipe stays fed. Compaction: per-lane 32-bit mask from the fp32 exponent
// bit (adj is exactly 0.0/1.0), wave shfl_up prefix-sum, short bit loop.
// Packed u16 edge list written into d_out row (512 B), consumed by kB.
// ---------------------------------------------------------------------------
__global__ __launch_bounds__(256) void k_scan(
    const float* __restrict__ adj, unsigned* __restrict__ cnt,
    unsigned* __restrict__ outw)
{
    __shared__ unsigned short sjl[4][MAXEG];
    const int tid  = threadIdx.x;
    const int wid  = tid >> 6;
    const int lane = tid & 63;
    const int row  = blockIdx.x * 4 + wid;
    const uvec4* rowp = (const uvec4*)(adj + (size_t)row * NN);
    unsigned wcnt = 0;

    #pragma unroll
    for (int b = 0; b < 4; ++b) {
        uvec4 v[8];
        #pragma unroll
        for (int it = 0; it < 8; ++it)
            v[it] = __builtin_nontemporal_load(rowp + b * 512 + it * 64 + lane);

        // bitmask: bit (it*4+c) set iff component c of v[it] is nonzero.
        // fp32 1.0 = 0x3F800000 -> bit23 is the 0/1 discriminator.
        unsigned lm = 0;
        #pragma unroll
        for (int it = 0; it < 8; ++it) {
            const unsigned m4 = ((v[it].x >> 23) & 1u) | ((v[it].y >> 22) & 2u) |
                                ((v[it].z >> 21) & 4u) | ((v[it].w >> 20) & 8u);
            lm |= m4 << (it * 4);
        }

        const int lc = __popc(lm);
        int pre = lc;
        #pragma unroll
        for (int off = 1; off < 64; off <<= 1) {
            const int t = __shfl_up(pre, off, 64);
            if (lane >= off) pre += t;
        }
        unsigned basep = wcnt + (unsigned)(pre - lc);
        wcnt += (unsigned)__shfl(pre, 63, 64);

        unsigned mm = lm;
        while (mm) {
            const int bit = __builtin_ctz(mm);
            mm &= mm - 1;
            const unsigned j = (unsigned)((b * 512 + (bit >> 2) * 64 + lane) * 4 + (bit & 3));
            if (basep < MAXEG) sjl[wid][basep] = (unsigned short)j;
            ++basep;
        }
    }

    asm volatile("s_waitcnt lgkmcnt(0)" ::: "memory");
    #pragma unroll
    for (int r = 0; r < 2; ++r) {
        const int k = lane + r * 64;
        const unsigned w = (unsigned)sjl[wid][2 * k] | ((unsigned)sjl[wid][2 * k + 1] << 16);
        outw[(size_t)row * 128 + k] = w;
    }
    if (lane == 0) cnt[row] = min(wcnt, (unsigned)MAXEG);
}

// ---------------------------------------------------------------------------
// Kernel B: wave-per-row softmax + gather. No block barriers.
// Reads packed edge list from out row i, overwrites out row i at the end.
// ---------------------------------------------------------------------------
__global__ __launch_bounds__(256) void kB(
    const float* __restrict__ h, const float* __restrict__ f1,
    const float* __restrict__ f2, const unsigned* __restrict__ cnt,
    float* __restrict__ out)
{
    __shared__ unsigned short jl[4][MAXEG];
    __shared__ float vl[4][MAXEG];
    const int tid  = threadIdx.x;
    const int wid  = tid >> 6;
    const int lane = tid & 63;
    const int i    = blockIdx.x * 4 + wid;
    const int n    = (int)cnt[i];
    const int c    = lane * 2;

    if (n == 0) {
        *(float2*)(out + (size_t)i * COUT + c) = make_float2(0.f, 0.f);
        return;   // wave-uniform exit
    }

    #pragma unroll
    for (int r = 0; r < 2; ++r) {
        const int k = lane + r * 64;
        const unsigned w = ((const unsigned*)out)[(size_t)i * 128 + k];
        jl[wid][2 * k]     = (unsigned short)(w & 0xffffu);
        jl[wid][2 * k + 1] = (unsigned short)(w >> 16);
    }
    asm volatile("s_waitcnt lgkmcnt(0)" ::: "memory");

    const float f1i = f1[i];
    float m = -1e30f;
    #pragma unroll
    for (int q = 0; q < 4; ++q) {
        const int p = lane + q * 64;
        if (p < n) {
            const float x = f1i + f2[jl[wid][p]];
            const float s = 1.f / (1.f + __expf(-x)) - 0.5f;
            vl[wid][p] = s;
            m = fmaxf(m, s);
        }
    }
    #pragma unroll
    for (int off = 32; off; off >>= 1) m = fmaxf(m, __shfl_xor(m, off, 64));

    float ssum = 0.f;
    #pragma unroll
    for (int q = 0; q < 4; ++q) {
        const int p = lane + q * 64;
        if (p < n) {
            const float e = __expf(vl[wid][p] - m);
            vl[wid][p] = e;
            ssum += e;
        }
    }
    #pragma unroll
    for (int off = 32; off; off >>= 1) ssum += __shfl_xor(ssum, off, 64);
    const float inv = 1.f / ssum;
    asm volatile("s_waitcnt lgkmcnt(0)" ::: "memory");

    // weighted gather: lane owns cols [2l,2l+1]; 4-deep unroll over edges.
    float ax = 0.f, ay = 0.f;
    int p = 0;
    for (; p + 3 < n; p += 4) {
        const int   j0 = jl[wid][p],     j1 = jl[wid][p + 1];
        const int   j2 = jl[wid][p + 2], j3 = jl[wid][p + 3];
        const float w0 = vl[wid][p],     w1 = vl[wid][p + 1];
        const float w2 = vl[wid][p + 2], w3 = vl[wid][p + 3];
        const float2 a0 = *(const float2*)(h + (size_t)j0 * COUT + c);
        const float2 a1 = *(const float2*)(h + (size_t)j1 * COUT + c);
        const float2 a2 = *(const float2*)(h + (size_t)j2 * COUT + c);
        const float2 a3 = *(const float2*)(h + (size_t)j3 * COUT + c);
        ax += w0 * a0.x + w1 * a1.x + w2 * a2.x + w3 * a3.x;
        ay += w0 * a0.y + w1 * a1.y + w2 * a2.y + w3 * a3.y;
    }
    for (; p < n; ++p) {
        const int   j = jl[wid][p];
        const float w = vl[wid][p];
        const float2 a = *(const float2*)(h + (size_t)j * COUT + c);
        ax += w * a.x;
        ay += w * a.y;
    }
    *(float2*)(out + (size_t)i * COUT + c) = make_float2(ax * inv, ay * inv);
}

extern "C" void kernel_launch(void* const* d_in, const int* in_sizes, int n_in,
                              void* d_out, int out_size, void* d_ws, size_t ws_size,
                              hipStream_t stream) {
    const float* X   = (const float*)d_in[0];
    const float* adj = (const float*)d_in[1];
    const float* W   = (const float*)d_in[2];
    const float* b   = (const float*)d_in[3];
    const float* v0  = (const float*)d_in[4];
    const float* v1  = (const float*)d_in[5];
    float* out = (float*)d_out;

    float*    h   = (float*)d_ws;                  // 8192*128 f32 = 4 MB
    float*    f1  = h + (size_t)NN * COUT;         // 32 KB
    float*    f2  = f1 + NN;                       // 32 KB
    unsigned* cnt = (unsigned*)(f2 + NN);          // 32 KB

    k1_gemm<<<NN / 16, 256, 0, stream>>>(X, W, b, v0, v1, h, f1, f2);
    k_scan<<<NN / 4, 256, 0, stream>>>(adj, cnt, (unsigned*)out);
    kB<<<NN / 4, 256, 0, stream>>>(h, f1, f2, cnt, out);
}

// Round 7
// 94.335 us; speedup vs baseline: 1.5174x; 1.0579x over previous
//
#include <hip/hip_runtime.h>
#include <math.h>

#define NN    8192
#define CIN   256
#define COUT  128
#define MAXEG 256      // max edges kept per row (mean ~82, sigma ~9 -> 19 sigma)

typedef unsigned uvec4 __attribute__((ext_vector_type(4)));

// ---------------------------------------------------------------------------
// Kernel 1: h = X@W + b ; f1 = h@v0 ; f2 = h@v1  (fp32, 16 rows x 128 cols/blk)
// ---------------------------------------------------------------------------
__global__ __launch_bounds__(256) void k1_gemm(
    const float* __restrict__ X, const float* __restrict__ W,
    const float* __restrict__ b, const float* __restrict__ v0,
    const float* __restrict__ v1,
    float* __restrict__ h, float* __restrict__ f1, float* __restrict__ f2)
{
    __shared__ float Xs[16][32];
    const int tid = threadIdx.x;
    const int ct  = tid & 63;
    const int rg  = tid >> 6;
    const int c   = ct * 2;
    const int row0 = blockIdx.x * 16;

    float acc[4][2] = {{0.f,0.f},{0.f,0.f},{0.f,0.f},{0.f,0.f}};

    for (int kc = 0; kc < CIN; kc += 32) {
        if (tid < 128) {
            const int r = tid >> 3, q = tid & 7;
            const float4 xv = *(const float4*)(X + (size_t)(row0 + r) * CIN + kc + q * 4);
            *(float4*)&Xs[r][q * 4] = xv;
        }
        float2 wv[32];
        #pragma unroll
        for (int kk = 0; kk < 32; ++kk)
            wv[kk] = *(const float2*)(W + (size_t)(kc + kk) * COUT + c);
        __syncthreads();

        #pragma unroll
        for (int rr = 0; rr < 4; ++rr) {
            const int lr = rg * 4 + rr;
            #pragma unroll
            for (int k4 = 0; k4 < 8; ++k4) {
                const float4 xv = *(const float4*)&Xs[lr][k4 * 4];
                acc[rr][0] += xv.x * wv[k4*4+0].x; acc[rr][1] += xv.x * wv[k4*4+0].y;
                acc[rr][0] += xv.y * wv[k4*4+1].x; acc[rr][1] += xv.y * wv[k4*4+1].y;
                acc[rr][0] += xv.z * wv[k4*4+2].x; acc[rr][1] += xv.z * wv[k4*4+2].y;
                acc[rr][0] += xv.w * wv[k4*4+3].x; acc[rr][1] += xv.w * wv[k4*4+3].y;
            }
        }
        __syncthreads();
    }

    const float b0 = b[c], b1 = b[c+1];
    const float v00 = v0[c], v01 = v0[c+1];
    const float v10 = v1[c], v11 = v1[c+1];

    #pragma unroll
    for (int rr = 0; rr < 4; ++rr) {
        const int row = row0 + rg * 4 + rr;
        const float h0 = acc[rr][0] + b0;
        const float h1 = acc[rr][1] + b1;
        *(float2*)(h + (size_t)row * COUT + c) = make_float2(h0, h1);
        float p0 = h0 * v00 + h1 * v01;
        float p1 = h0 * v10 + h1 * v11;
        #pragma unroll
        for (int off = 32; off; off >>= 1) {
            p0 += __shfl_down(p0, off, 64);
            p1 += __shfl_down(p1, off, 64);
        }
        if (ct == 0) { f1[row] = p0; f2[row] = p1; }
    }
}

// ---------------------------------------------------------------------------
// Kernel 2: fused wave-per-row scan + softmax + gather. No block barriers.
// Scan is software-pipelined (va/vb double buffer): batch b+2's loads are
// issued BEFORE batch b's compute, so each wave keeps 8-16 global loads in
// flight for the whole scan phase. Plain (non-nt) loads.
// After the scan, the same wave runs softmax + h-gather from its own LDS
// edge list -- the L2 gather of late waves overlaps the HBM stream of
// earlier-phase waves at CU level without any synchronization.
// ---------------------------------------------------------------------------
__global__ __launch_bounds__(256) void k2_fused(
    const float* __restrict__ adj, const float* __restrict__ h,
    const float* __restrict__ f1, const float* __restrict__ f2,
    float* __restrict__ out)
{
    __shared__ unsigned short sjl[4][MAXEG];
    __shared__ float vl[4][MAXEG];

    const int tid  = threadIdx.x;
    const int wid  = tid >> 6;
    const int lane = tid & 63;
    const int row  = blockIdx.x * 4 + wid;
    const uvec4* rowp = (const uvec4*)(adj + (size_t)row * NN) + lane;

    unsigned wcnt = 0;
    uvec4 va[8], vb[8];

    // mask -> prefix-sum -> LDS compact for one 8KB batch held in registers
    auto process = [&](const uvec4 (&v)[8], const int b) {
        unsigned lm = 0;
        #pragma unroll
        for (int it = 0; it < 8; ++it) {
            // adj is exactly 0.0f or 1.0f: fp32 1.0 = 0x3F800000 -> bit23.
            const unsigned m4 = ((v[it].x >> 23) & 1u) | ((v[it].y >> 22) & 2u) |
                                ((v[it].z >> 21) & 4u) | ((v[it].w >> 20) & 8u);
            lm |= m4 << (it * 4);
        }
        const int lc = __popc(lm);
        int pre = lc;
        #pragma unroll
        for (int off = 1; off < 64; off <<= 1) {
            const int t = __shfl_up(pre, off, 64);
            if (lane >= off) pre += t;
        }
        unsigned basep = wcnt + (unsigned)(pre - lc);
        wcnt += (unsigned)__shfl(pre, 63, 64);
        unsigned mm = lm;
        while (mm) {
            const int bit = __builtin_ctz(mm);
            mm &= mm - 1;
            const unsigned j = (unsigned)((b * 512 + (bit >> 2) * 64 + lane) * 4 + (bit & 3));
            if (basep < MAXEG) sjl[wid][basep] = (unsigned short)j;
            ++basep;
        }
    };

    // ---- software-pipelined scan: loads for b+2 issue before compute of b ----
    #pragma unroll
    for (int it = 0; it < 8; ++it) va[it] = rowp[0 * 512 + it * 64];
    #pragma unroll
    for (int it = 0; it < 8; ++it) vb[it] = rowp[1 * 512 + it * 64];
    process(va, 0);
    #pragma unroll
    for (int it = 0; it < 8; ++it) va[it] = rowp[2 * 512 + it * 64];
    process(vb, 1);
    #pragma unroll
    for (int it = 0; it < 8; ++it) vb[it] = rowp[3 * 512 + it * 64];
    process(va, 2);
    process(vb, 3);

    const int n = min((int)wcnt, MAXEG);
    const int c = lane * 2;
    if (n == 0) {   // wave-uniform exit
        *(float2*)(out + (size_t)row * COUT + c) = make_float2(0.f, 0.f);
        return;
    }

    asm volatile("s_waitcnt lgkmcnt(0)" ::: "memory");

    // ---- softmax over n <= 256 edges (lane handles p = lane + q*64) ----
    const float f1i = f1[row];
    float m = -1e30f;
    #pragma unroll
    for (int q = 0; q < 4; ++q) {
        const int p = lane + q * 64;
        if (p < n) {
            const float x = f1i + f2[sjl[wid][p]];
            const float s = 1.f / (1.f + __expf(-x)) - 0.5f;
            vl[wid][p] = s;
            m = fmaxf(m, s);
        }
    }
    #pragma unroll
    for (int off = 32; off; off >>= 1) m = fmaxf(m, __shfl_xor(m, off, 64));

    float ssum = 0.f;
    #pragma unroll
    for (int q = 0; q < 4; ++q) {
        const int p = lane + q * 64;
        if (p < n) {
            const float e = __expf(vl[wid][p] - m);
            vl[wid][p] = e;
            ssum += e;
        }
    }
    #pragma unroll
    for (int off = 32; off; off >>= 1) ssum += __shfl_xor(ssum, off, 64);
    const float inv = 1.f / ssum;
    asm volatile("s_waitcnt lgkmcnt(0)" ::: "memory");

    // ---- weighted gather of h rows: lane owns cols [2l,2l+1], 8-deep ILP ----
    float ax = 0.f, ay = 0.f;
    int p = 0;
    for (; p + 7 < n; p += 8) {
        int   jj[8];
        float ww[8];
        float2 aa[8];
        #pragma unroll
        for (int u = 0; u < 8; ++u) { jj[u] = sjl[wid][p + u]; ww[u] = vl[wid][p + u]; }
        #pragma unroll
        for (int u = 0; u < 8; ++u) aa[u] = *(const float2*)(h + (size_t)jj[u] * COUT + c);
        #pragma unroll
        for (int u = 0; u < 8; ++u) { ax += ww[u] * aa[u].x; ay += ww[u] * aa[u].y; }
    }
    for (; p < n; ++p) {
        const int   j = sjl[wid][p];
        const float w = vl[wid][p];
        const float2 a = *(const float2*)(h + (size_t)j * COUT + c);
        ax += w * a.x;
        ay += w * a.y;
    }
    *(float2*)(out + (size_t)row * COUT + c) = make_float2(ax * inv, ay * inv);
}

extern "C" void kernel_launch(void* const* d_in, const int* in_sizes, int n_in,
                              void* d_out, int out_size, void* d_ws, size_t ws_size,
                              hipStream_t stream) {
    const float* X   = (const float*)d_in[0];
    const float* adj = (const float*)d_in[1];
    const float* W   = (const float*)d_in[2];
    const float* b   = (const float*)d_in[3];
    const float* v0  = (const float*)d_in[4];
    const float* v1  = (const float*)d_in[5];
    float* out = (float*)d_out;

    float* h  = (float*)d_ws;                 // 8192*128 f32 = 4 MB
    float* f1 = h + (size_t)NN * COUT;        // 32 KB
    float* f2 = f1 + NN;                      // 32 KB

    k1_gemm<<<NN / 16, 256, 0, stream>>>(X, W, b, v0, v1, h, f1, f2);
    k2_fused<<<NN / 4, 256, 0, stream>>>(adj, h, f1, f2, out);
}